// Round 2
// baseline (320.017 us; speedup 1.0000x reference)
//
#include <hip/hip_runtime.h>
#include <stdint.h>

#define NBINS 4096
#define CAP   65536
#define SRATE 64  // sample every 64th point for the threshold estimate

// Distance key: f32 bit pattern of sqrt((dx*dx + dy*dy) + dz*dz), computed with
// explicit round-to-nearest intrinsics so hipcc cannot FMA-contract and diverge
// from the numpy reference. Non-negative floats are order-isomorphic to their
// uint32 bit patterns.
__device__ __forceinline__ uint32_t dist_key(float x, float y, float z,
                                             float px, float py, float pz) {
    float dx = __fsub_rn(x, px);
    float dy = __fsub_rn(y, py);
    float dz = __fsub_rn(z, pz);
    float s = __fadd_rn(__fadd_rn(__fmul_rn(dx, dx), __fmul_rn(dy, dy)),
                        __fmul_rn(dz, dz));
    float d = __fsqrt_rn(s);
    return __float_as_uint(d);
}

__global__ void __launch_bounds__(256) zero_kernel(uint32_t* p, int n) {
    int i = blockIdx.x * 256 + threadIdx.x;
    if (i < n) p[i] = 0;
}

// Histogram of every SRATE-th point only. Samples are a subset of the full
// set, so the sampled K-th smallest is an upper bound on the true K-th
// smallest: cum_sampled(<=cut) >= K  ==>  cum_full(<=cut) >= K. Exact, no
// probabilistic fallback needed.
__global__ void __launch_bounds__(256) sample_hist_kernel(const float* __restrict__ pts,
                                                          const float* __restrict__ P1,
                                                          uint32_t* __restrict__ ghist,
                                                          int nsamp) {
    __shared__ uint32_t lh[NBINS];
    for (int i = threadIdx.x; i < NBINS; i += 256) lh[i] = 0;
    __syncthreads();
    float px = P1[0], py = P1[1], pz = P1[2];
    int gid = blockIdx.x * 256 + threadIdx.x;
    int stride = gridDim.x * 256;
    for (int s = gid; s < nsamp; s += stride) {
        int i = s * SRATE;
        uint32_t k = dist_key(pts[3 * i], pts[3 * i + 1], pts[3 * i + 2], px, py, pz);
        atomicAdd(&lh[k >> 20], 1u);
    }
    __syncthreads();
    for (int i = threadIdx.x; i < NBINS; i += 256) {
        uint32_t v = lh[i];
        if (v) atomicAdd(&ghist[i], v);
    }
}

__global__ void __launch_bounds__(256) scan_kernel(const uint32_t* __restrict__ ghist,
                                                   uint32_t* __restrict__ cut, int K) {
    __shared__ uint32_t s[256];
    int t = threadIdx.x;
    uint32_t mine[16];
    uint32_t local = 0;
    for (int j = 0; j < 16; ++j) {
        mine[j] = ghist[t * 16 + j];
        local += mine[j];
    }
    s[t] = local;
    __syncthreads();
    // Hillis-Steele inclusive scan over 256 chunk sums
    for (int off = 1; off < 256; off <<= 1) {
        uint32_t v = (t >= off) ? s[t - off] : 0;
        __syncthreads();
        s[t] += v;
        __syncthreads();
    }
    uint32_t incl = s[t];
    uint32_t excl = incl - local;
    if (excl < (uint32_t)K && incl >= (uint32_t)K) {
        uint32_t run = excl;
        for (int j = 0; j < 16; ++j) {
            run += mine[j];
            if (run >= (uint32_t)K) {
                *cut = (uint32_t)(t * 16 + j);
                break;
            }
        }
    }
}

// Single full pass: append (key,idx) packed as u64 for all points whose bin
// is <= cut. Expected M ~ SRATE*K*~1.4 ~ 6K; guaranteed M >= K.
__global__ void __launch_bounds__(256) filter_kernel(const float* __restrict__ pts,
                                                     const float* __restrict__ P1,
                                                     const uint32_t* __restrict__ cut,
                                                     uint32_t* __restrict__ cnt,
                                                     unsigned long long* __restrict__ cand,
                                                     int nquads, int N) {
    float px = P1[0], py = P1[1], pz = P1[2];
    uint32_t cb = *cut;
    int gid = blockIdx.x * 256 + threadIdx.x;
    int stride = gridDim.x * 256;
    const float4* p4 = (const float4*)pts;
    for (int q = gid; q < nquads; q += stride) {
        float4 a = p4[q * 3 + 0];
        float4 b = p4[q * 3 + 1];
        float4 c = p4[q * 3 + 2];
        uint32_t k[4];
        k[0] = dist_key(a.x, a.y, a.z, px, py, pz);
        k[1] = dist_key(a.w, b.x, b.y, px, py, pz);
        k[2] = dist_key(b.z, b.w, c.x, px, py, pz);
        k[3] = dist_key(c.y, c.z, c.w, px, py, pz);
        #pragma unroll
        for (int j = 0; j < 4; ++j) {
            if ((k[j] >> 20) <= cb) {
                uint32_t pos = atomicAdd(cnt, 1u);
                if (pos < CAP) {
                    cand[pos] = ((unsigned long long)k[j] << 32) |
                                (unsigned long long)(uint32_t)(q * 4 + j);
                }
            }
        }
    }
    if (gid == 0) {
        for (int i = nquads * 4; i < N; ++i) {
            uint32_t kk = dist_key(pts[3 * i], pts[3 * i + 1], pts[3 * i + 2], px, py, pz);
            if ((kk >> 20) <= cb) {
                uint32_t pos = atomicAdd(cnt, 1u);
                if (pos < CAP) {
                    cand[pos] = ((unsigned long long)kk << 32) | (unsigned long long)(uint32_t)i;
                }
            }
        }
    }
}

// Rank-based exact selection: candidate i's output slot is its exact rank by
// composite (key<<32)|idx — identical ordering + tie-break (lower index first)
// to jax.lax.top_k on -dist. Composites are unique, so ranks 0..M-1 are a
// permutation; M >= K guarantees every rank < K is written exactly once.
__global__ void __launch_bounds__(256) select_kernel(const uint32_t* __restrict__ cnt,
                                                     const unsigned long long* __restrict__ cand,
                                                     const float* __restrict__ pts,
                                                     float* __restrict__ out, int K) {
    uint32_t M = *cnt;
    if (M > CAP) M = CAP;
    uint32_t stride = gridDim.x * 256;
    for (uint32_t i = blockIdx.x * 256 + threadIdx.x; i < M; i += stride) {
        unsigned long long ci = cand[i];
        uint32_t r = 0;
        for (uint32_t j = 0; j < M; ++j) {
            r += (cand[j] < ci) ? 1u : 0u;
        }
        if (r < (uint32_t)K) {
            uint32_t idx = (uint32_t)(ci & 0xFFFFFFFFu);
            out[3 * r + 0] = pts[3 * idx + 0];
            out[3 * r + 1] = pts[3 * idx + 1];
            out[3 * r + 2] = pts[3 * idx + 2];
            out[3 * K + r] = (float)idx;  // indices exactly representable (< 2^23)
        }
    }
}

extern "C" void kernel_launch(void* const* d_in, const int* in_sizes, int n_in,
                              void* d_out, int out_size, void* d_ws, size_t ws_size,
                              hipStream_t stream) {
    const float* pts = (const float*)d_in[0];
    const float* P1  = (const float*)d_in[1];
    float* out = (float*)d_out;

    int N = in_sizes[0] / 3;
    int nquads = N / 4;
    int K = out_size / 4;  // out = K*3 coords + K indices
    int nsamp = N / SRATE; // 131072 for 8M points; always >= K here

    uint32_t* w    = (uint32_t*)d_ws;
    uint32_t* cnt  = w + 0;
    uint32_t* cut  = w + 1;
    uint32_t* hist = w + 4;  // NBINS
    unsigned long long* cand = (unsigned long long*)(w + 4 + NBINS);  // CAP u64, 8B-aligned

    int zn = 4 + NBINS;
    zero_kernel<<<(zn + 255) / 256, 256, 0, stream>>>(w, zn);
    sample_hist_kernel<<<64, 256, 0, stream>>>(pts, P1, hist, nsamp);
    scan_kernel<<<1, 256, 0, stream>>>(hist, cut, K);
    filter_kernel<<<2048, 256, 0, stream>>>(pts, P1, cut, cnt, cand, nquads, N);
    select_kernel<<<64, 256, 0, stream>>>(cnt, cand, pts, out, K);
}

// Round 3
// 85.283 us; speedup vs baseline: 3.7524x; 3.7524x over previous
//
#include <hip/hip_runtime.h>
#include <stdint.h>

#define NBINS 4096
#define NB2   4096
#define CAP   32768
#define LDS_CAND 8192
#define SRATE 64  // sample every 64th point for the threshold estimate

// Distance key: f32 bit pattern of sqrt((dx*dx + dy*dy) + dz*dz), computed with
// explicit round-to-nearest intrinsics so hipcc cannot FMA-contract and diverge
// from the numpy reference. Non-negative floats are order-isomorphic to their
// uint32 bit patterns.
__device__ __forceinline__ uint32_t dist_key(float x, float y, float z,
                                             float px, float py, float pz) {
    float dx = __fsub_rn(x, px);
    float dy = __fsub_rn(y, py);
    float dz = __fsub_rn(z, pz);
    float s = __fadd_rn(__fadd_rn(__fmul_rn(dx, dx), __fmul_rn(dy, dy)),
                        __fmul_rn(dz, dz));
    float d = __fsqrt_rn(s);
    return __float_as_uint(d);
}

__global__ void __launch_bounds__(256) zero_kernel(uint32_t* p, int n) {
    int i = blockIdx.x * 256 + threadIdx.x;
    if (i < n) p[i] = 0;
}

// Histogram of every SRATE-th point. Samples are a subset of the full set, so
// cum_sampled(<=cut) >= K  ==>  cum_full(<=cut) >= K: the cut is exact-safe.
__global__ void __launch_bounds__(256) sample_hist_kernel(const float* __restrict__ pts,
                                                          const float* __restrict__ P1,
                                                          uint32_t* __restrict__ ghist,
                                                          int nsamp) {
    __shared__ uint32_t lh[NBINS];
    for (int i = threadIdx.x; i < NBINS; i += 256) lh[i] = 0;
    __syncthreads();
    float px = P1[0], py = P1[1], pz = P1[2];
    int gid = blockIdx.x * 256 + threadIdx.x;
    int stride = gridDim.x * 256;
    for (int s = gid; s < nsamp; s += stride) {
        int i = s * SRATE;
        uint32_t k = dist_key(pts[3 * i], pts[3 * i + 1], pts[3 * i + 2], px, py, pz);
        atomicAdd(&lh[k >> 20], 1u);
    }
    __syncthreads();
    for (int i = threadIdx.x; i < NBINS; i += 256) {
        uint32_t v = lh[i];
        if (v) atomicAdd(&ghist[i], v);
    }
}

__global__ void __launch_bounds__(256) scan_kernel(const uint32_t* __restrict__ ghist,
                                                   uint32_t* __restrict__ cut, int K) {
    __shared__ uint32_t s[256];
    int t = threadIdx.x;
    uint32_t mine[16];
    uint32_t local = 0;
    for (int j = 0; j < 16; ++j) {
        mine[j] = ghist[t * 16 + j];
        local += mine[j];
    }
    s[t] = local;
    __syncthreads();
    for (int off = 1; off < 256; off <<= 1) {
        uint32_t v = (t >= off) ? s[t - off] : 0;
        __syncthreads();
        s[t] += v;
        __syncthreads();
    }
    uint32_t incl = s[t];
    uint32_t excl = incl - local;
    if (excl < (uint32_t)K && incl >= (uint32_t)K) {
        uint32_t run = excl;
        for (int j = 0; j < 16; ++j) {
            run += mine[j];
            if (run >= (uint32_t)K) {
                *cut = (uint32_t)(t * 16 + j);
                break;
            }
        }
    }
}

// Full-data pass: append (key<<32)|idx for points with bin <= cut.
__global__ void __launch_bounds__(256) filter_kernel(const float* __restrict__ pts,
                                                     const float* __restrict__ P1,
                                                     const uint32_t* __restrict__ cut,
                                                     uint32_t* __restrict__ cnt,
                                                     unsigned long long* __restrict__ cand,
                                                     int nquads, int N) {
    float px = P1[0], py = P1[1], pz = P1[2];
    uint32_t cb = *cut;
    int gid = blockIdx.x * 256 + threadIdx.x;
    int stride = gridDim.x * 256;
    const float4* p4 = (const float4*)pts;
    for (int q = gid; q < nquads; q += stride) {
        float4 a = p4[q * 3 + 0];
        float4 b = p4[q * 3 + 1];
        float4 c = p4[q * 3 + 2];
        uint32_t k[4];
        k[0] = dist_key(a.x, a.y, a.z, px, py, pz);
        k[1] = dist_key(a.w, b.x, b.y, px, py, pz);
        k[2] = dist_key(b.z, b.w, c.x, px, py, pz);
        k[3] = dist_key(c.y, c.z, c.w, px, py, pz);
        #pragma unroll
        for (int j = 0; j < 4; ++j) {
            if ((k[j] >> 20) <= cb) {
                uint32_t pos = atomicAdd(cnt, 1u);
                if (pos < CAP) {
                    cand[pos] = ((unsigned long long)k[j] << 32) |
                                (unsigned long long)(uint32_t)(q * 4 + j);
                }
            }
        }
    }
    if (gid == 0) {
        for (int i = nquads * 4; i < N; ++i) {
            uint32_t kk = dist_key(pts[3 * i], pts[3 * i + 1], pts[3 * i + 2], px, py, pz);
            if ((kk >> 20) <= cb) {
                uint32_t pos = atomicAdd(cnt, 1u);
                if (pos < CAP) {
                    cand[pos] = ((unsigned long long)kk << 32) | (unsigned long long)(uint32_t)i;
                }
            }
        }
    }
}

// Single-block refine + exact select over the M candidates:
//  1. LDS histogram of keys into NB2 linear sub-bins of [0, (cb+1)<<20)
//     (bin = key*NB2/R, monotone => exact threshold semantics).
//  2. LDS scan -> cut2 = first sub-bin with cum >= K (count(b<=cut2) >= K).
//  3. Compact qualifiers to LDS (+ global mirror for the degenerate-overflow
//     fallback). Expected M2 ~ K + O(1).
//  4. Exact rank by composite (key<<32)|idx among M2: identical order and
//     tie-break (lower index first) to jax.lax.top_k(-dist). Ranks are a
//     permutation; every rank < K is written exactly once.
__global__ void __launch_bounds__(1024) refine_select_kernel(
        const uint32_t* __restrict__ cnt,
        const uint32_t* __restrict__ cut,
        const unsigned long long* __restrict__ cand,
        unsigned long long* __restrict__ cand2,
        const float* __restrict__ pts,
        float* __restrict__ out, int K) {
    __shared__ uint32_t hist2[NB2];
    __shared__ uint32_t ssum[1024];
    __shared__ unsigned long long lcand[LDS_CAND];
    __shared__ uint32_t cut2_s, m2_s;
    int t = threadIdx.x;
    uint32_t M = *cnt;
    if (M > CAP) M = CAP;
    uint32_t cb = *cut;
    unsigned long long R = ((unsigned long long)(cb + 1)) << 20;

    for (int i = t; i < NB2; i += 1024) hist2[i] = 0;
    if (t == 0) m2_s = 0;
    __syncthreads();
    for (uint32_t i = t; i < M; i += 1024) {
        uint32_t key = (uint32_t)(cand[i] >> 32);
        uint32_t b2 = (uint32_t)((((unsigned long long)key) << 12) / R);
        atomicAdd(&hist2[b2], 1u);
    }
    __syncthreads();

    uint32_t mine[4];
    uint32_t local = 0;
    for (int j = 0; j < 4; ++j) { mine[j] = hist2[t * 4 + j]; local += mine[j]; }
    ssum[t] = local;
    __syncthreads();
    for (int off = 1; off < 1024; off <<= 1) {
        uint32_t v = (t >= off) ? ssum[t - off] : 0;
        __syncthreads();
        ssum[t] += v;
        __syncthreads();
    }
    uint32_t incl = ssum[t], excl = incl - local;
    if (excl < (uint32_t)K && incl >= (uint32_t)K) {
        uint32_t run = excl;
        for (int j = 0; j < 4; ++j) {
            run += mine[j];
            if (run >= (uint32_t)K) { cut2_s = (uint32_t)(t * 4 + j); break; }
        }
    }
    __syncthreads();
    uint32_t c2 = cut2_s;

    for (uint32_t i = t; i < M; i += 1024) {
        unsigned long long cv = cand[i];
        uint32_t key = (uint32_t)(cv >> 32);
        uint32_t b2 = (uint32_t)((((unsigned long long)key) << 12) / R);
        if (b2 <= c2) {
            uint32_t pos = atomicAdd(&m2_s, 1u);
            if (pos < LDS_CAND) lcand[pos] = cv;
            cand2[pos] = cv;
        }
    }
    __syncthreads();
    uint32_t M2 = m2_s;

    if (M2 <= LDS_CAND) {
        // common path: everything in LDS; inner j-loop is a lane-uniform
        // broadcast read (conflict-free).
        for (uint32_t i = t; i < M2; i += 1024) {
            unsigned long long ci = lcand[i];
            uint32_t rank = 0;
            for (uint32_t j = 0; j < M2; ++j) rank += (lcand[j] < ci) ? 1u : 0u;
            if (rank < (uint32_t)K) {
                uint32_t idx = (uint32_t)(ci & 0xFFFFFFFFu);
                out[3 * rank + 0] = pts[3 * idx + 0];
                out[3 * rank + 1] = pts[3 * idx + 1];
                out[3 * rank + 2] = pts[3 * idx + 2];
                out[3 * K + rank] = (float)idx;
            }
        }
    } else {
        // degenerate fallback: rank against global mirror (L2-hot broadcast)
        for (uint32_t i = t; i < M2; i += 1024) {
            unsigned long long ci = cand2[i];
            uint32_t rank = 0;
            for (uint32_t j = 0; j < M2; ++j) rank += (cand2[j] < ci) ? 1u : 0u;
            if (rank < (uint32_t)K) {
                uint32_t idx = (uint32_t)(ci & 0xFFFFFFFFu);
                out[3 * rank + 0] = pts[3 * idx + 0];
                out[3 * rank + 1] = pts[3 * idx + 1];
                out[3 * rank + 2] = pts[3 * idx + 2];
                out[3 * K + rank] = (float)idx;
            }
        }
    }
}

extern "C" void kernel_launch(void* const* d_in, const int* in_sizes, int n_in,
                              void* d_out, int out_size, void* d_ws, size_t ws_size,
                              hipStream_t stream) {
    const float* pts = (const float*)d_in[0];
    const float* P1  = (const float*)d_in[1];
    float* out = (float*)d_out;

    int N = in_sizes[0] / 3;
    int nquads = N / 4;
    int K = out_size / 4;  // out = K*3 coords + K indices
    int nsamp = N / SRATE;

    uint32_t* w    = (uint32_t*)d_ws;
    uint32_t* cnt  = w + 0;
    uint32_t* cut  = w + 1;
    uint32_t* hist = w + 4;                                        // NBINS
    unsigned long long* cand  = (unsigned long long*)(w + 4 + NBINS);  // CAP u64
    unsigned long long* cand2 = cand + CAP;                            // CAP u64

    int zn = 4 + NBINS;
    zero_kernel<<<(zn + 255) / 256, 256, 0, stream>>>(w, zn);
    sample_hist_kernel<<<64, 256, 0, stream>>>(pts, P1, hist, nsamp);
    scan_kernel<<<1, 256, 0, stream>>>(hist, cut, K);
    filter_kernel<<<2048, 256, 0, stream>>>(pts, P1, cut, cnt, cand, nquads, N);
    refine_select_kernel<<<1, 1024, 0, stream>>>(cnt, cut, cand, cand2, pts, out, K);
}

// Round 4
// 84.568 us; speedup vs baseline: 3.7841x; 1.0085x over previous
//
#include <hip/hip_runtime.h>
#include <stdint.h>

#define NBINS 4096
#define NB2   4096
#define CAP   32768
#define LDS_CAND 8192
#define SRATE 64        // sample every 64th point for the threshold estimate
#define TILE_PTS 1024   // points per block-tile
#define TILE_F4  768    // float4s per tile  (TILE_PTS*3/4)
#define WSLICE_F4 192   // float4s per wave slice (3 KB)

typedef const __attribute__((address_space(1))) void* gas_ptr;
typedef __attribute__((address_space(3))) void* las_ptr;

// Distance key: f32 bit pattern of sqrt((dx*dx + dy*dy) + dz*dz), computed with
// explicit round-to-nearest intrinsics so hipcc cannot FMA-contract and diverge
// from the numpy reference. Non-negative floats are order-isomorphic to their
// uint32 bit patterns.
__device__ __forceinline__ uint32_t dist_key(float x, float y, float z,
                                             float px, float py, float pz) {
    float dx = __fsub_rn(x, px);
    float dy = __fsub_rn(y, py);
    float dz = __fsub_rn(z, pz);
    float s = __fadd_rn(__fadd_rn(__fmul_rn(dx, dx), __fmul_rn(dy, dy)),
                        __fmul_rn(dz, dz));
    float d = __fsqrt_rn(s);
    return __float_as_uint(d);
}

__global__ void __launch_bounds__(256) zero_kernel(uint32_t* p, int n) {
    int i = blockIdx.x * 256 + threadIdx.x;
    if (i < n) p[i] = 0;
}

// Histogram of every SRATE-th point. Samples are a subset of the full set, so
// cum_sampled(<=cut) >= K  ==>  cum_full(<=cut) >= K: the cut is exact-safe.
__global__ void __launch_bounds__(256) sample_hist_kernel(const float* __restrict__ pts,
                                                          const float* __restrict__ P1,
                                                          uint32_t* __restrict__ ghist,
                                                          int nsamp) {
    __shared__ uint32_t lh[NBINS];
    for (int i = threadIdx.x; i < NBINS; i += 256) lh[i] = 0;
    __syncthreads();
    float px = P1[0], py = P1[1], pz = P1[2];
    int gid = blockIdx.x * 256 + threadIdx.x;
    int stride = gridDim.x * 256;
    for (int s = gid; s < nsamp; s += stride) {
        int i = s * SRATE;
        uint32_t k = dist_key(pts[3 * i], pts[3 * i + 1], pts[3 * i + 2], px, py, pz);
        atomicAdd(&lh[k >> 20], 1u);
    }
    __syncthreads();
    for (int i = threadIdx.x; i < NBINS; i += 256) {
        uint32_t v = lh[i];
        if (v) atomicAdd(&ghist[i], v);
    }
}

__global__ void __launch_bounds__(256) scan_kernel(const uint32_t* __restrict__ ghist,
                                                   uint32_t* __restrict__ cut, int K) {
    __shared__ uint32_t s[256];
    int t = threadIdx.x;
    uint32_t mine[16];
    uint32_t local = 0;
    for (int j = 0; j < 16; ++j) {
        mine[j] = ghist[t * 16 + j];
        local += mine[j];
    }
    s[t] = local;
    __syncthreads();
    for (int off = 1; off < 256; off <<= 1) {
        uint32_t v = (t >= off) ? s[t - off] : 0;
        __syncthreads();
        s[t] += v;
        __syncthreads();
    }
    uint32_t incl = s[t];
    uint32_t excl = incl - local;
    if (excl < (uint32_t)K && incl >= (uint32_t)K) {
        uint32_t run = excl;
        for (int j = 0; j < 16; ++j) {
            run += mine[j];
            if (run >= (uint32_t)K) {
                *cut = (uint32_t)(t * 16 + j);
                break;
            }
        }
    }
}

// Full-data pass, LDS-staged. Each wave DMAs its own contiguous 3 KB slice of
// the tile via global_load_lds (3 x 1KB fully-coalesced instructions), then
// reads it back at 48 B/lane stride (conflict-free b128: banks
// {0,12,24,4,16,28,8,20} per 8-lane phase). Wave slices are disjoint -> no
// __syncthreads anywhere; double-buffered with per-wave vmcnt(0).
__global__ void __launch_bounds__(256) filter2_kernel(const float* __restrict__ pts,
                                                      const float* __restrict__ P1,
                                                      const uint32_t* __restrict__ cut,
                                                      uint32_t* __restrict__ cnt,
                                                      unsigned long long* __restrict__ cand,
                                                      int ntiles, int N) {
    __shared__ float4 lds[2][TILE_F4];
    const float4* p4 = (const float4*)pts;
    float px = P1[0], py = P1[1], pz = P1[2];
    uint32_t cb = *cut;
    int w = threadIdx.x >> 6;
    int lane = threadIdx.x & 63;
    int tp = threadIdx.x;   // handles points 4*tp..4*tp+3 of the tile
    int stride = gridDim.x;

    auto stage = [&](int b, int t) {
        const float4* s = p4 + (size_t)t * TILE_F4 + w * WSLICE_F4 + lane;
        float4* d = &lds[b][w * WSLICE_F4];
        __builtin_amdgcn_global_load_lds((gas_ptr)(s),       (las_ptr)(d),       16, 0, 0);
        __builtin_amdgcn_global_load_lds((gas_ptr)(s + 64),  (las_ptr)(d + 64),  16, 0, 0);
        __builtin_amdgcn_global_load_lds((gas_ptr)(s + 128), (las_ptr)(d + 128), 16, 0, 0);
    };

    int t = blockIdx.x;
    int b = 0;
    if (t < ntiles) stage(0, t);
    for (; t < ntiles; t += stride, b ^= 1) {
        int tn = t + stride;
        asm volatile("s_waitcnt vmcnt(0)" ::: "memory");
        const float* fb = (const float*)(&lds[b][0]) + tp * 12;
        float4 A = *(const float4*)(fb);
        float4 Bv = *(const float4*)(fb + 4);
        float4 Cv = *(const float4*)(fb + 8);
        // issue next tile's DMA before the (rare) appends so its latency
        // overlaps compute; next iteration's vmcnt(0) drains it.
        if (tn < ntiles) stage(b ^ 1, tn);
        uint32_t kk[4];
        kk[0] = dist_key(A.x, A.y, A.z, px, py, pz);
        kk[1] = dist_key(A.w, Bv.x, Bv.y, px, py, pz);
        kk[2] = dist_key(Bv.z, Bv.w, Cv.x, px, py, pz);
        kk[3] = dist_key(Cv.y, Cv.z, Cv.w, px, py, pz);
        uint32_t pbase = (uint32_t)t * TILE_PTS + (uint32_t)tp * 4;
        #pragma unroll
        for (int j = 0; j < 4; ++j) {
            if ((kk[j] >> 20) <= cb) {
                uint32_t pos = atomicAdd(cnt, 1u);
                if (pos < CAP) {
                    cand[pos] = ((unsigned long long)kk[j] << 32) |
                                (unsigned long long)(pbase + j);
                }
            }
        }
    }
    // tail (N not a multiple of TILE_PTS)
    if (blockIdx.x == 0 && threadIdx.x == 0) {
        for (int i = ntiles * TILE_PTS; i < N; ++i) {
            uint32_t kk = dist_key(pts[3 * i], pts[3 * i + 1], pts[3 * i + 2], px, py, pz);
            if ((kk >> 20) <= cb) {
                uint32_t pos = atomicAdd(cnt, 1u);
                if (pos < CAP) {
                    cand[pos] = ((unsigned long long)kk << 32) | (unsigned long long)(uint32_t)i;
                }
            }
        }
    }
}

// Single-block refine + exact select over the M candidates (see round-2 notes).
// Binning uses a monotone multiply-shift (no per-candidate u64 division).
__global__ void __launch_bounds__(1024) refine_select_kernel(
        const uint32_t* __restrict__ cnt,
        const uint32_t* __restrict__ cut,
        const unsigned long long* __restrict__ cand,
        unsigned long long* __restrict__ cand2,
        const float* __restrict__ pts,
        float* __restrict__ out, int K) {
    __shared__ uint32_t hist2[NB2];
    __shared__ uint32_t ssum[1024];
    __shared__ unsigned long long lcand[LDS_CAND];
    __shared__ uint32_t cut2_s, m2_s;
    int t = threadIdx.x;
    uint32_t M = *cnt;
    if (M > CAP) M = CAP;
    uint32_t cb = *cut;
    unsigned long long R = ((unsigned long long)(cb + 1)) << 20;
    // monotone map key -> bin: (key * M32) >> 32 < NB2 for key < R
    uint32_t M32 = (uint32_t)((((unsigned long long)NB2) << 32) / R);

    for (int i = t; i < NB2; i += 1024) hist2[i] = 0;
    if (t == 0) m2_s = 0;
    __syncthreads();
    for (uint32_t i = t; i < M; i += 1024) {
        uint32_t key = (uint32_t)(cand[i] >> 32);
        uint32_t b2 = (uint32_t)(((unsigned long long)key * M32) >> 32);
        atomicAdd(&hist2[b2], 1u);
    }
    __syncthreads();

    uint32_t mine[4];
    uint32_t local = 0;
    for (int j = 0; j < 4; ++j) { mine[j] = hist2[t * 4 + j]; local += mine[j]; }
    ssum[t] = local;
    __syncthreads();
    for (int off = 1; off < 1024; off <<= 1) {
        uint32_t v = (t >= off) ? ssum[t - off] : 0;
        __syncthreads();
        ssum[t] += v;
        __syncthreads();
    }
    uint32_t incl = ssum[t], excl = incl - local;
    if (excl < (uint32_t)K && incl >= (uint32_t)K) {
        uint32_t run = excl;
        for (int j = 0; j < 4; ++j) {
            run += mine[j];
            if (run >= (uint32_t)K) { cut2_s = (uint32_t)(t * 4 + j); break; }
        }
    }
    __syncthreads();
    uint32_t c2 = cut2_s;

    for (uint32_t i = t; i < M; i += 1024) {
        unsigned long long cv = cand[i];
        uint32_t key = (uint32_t)(cv >> 32);
        uint32_t b2 = (uint32_t)(((unsigned long long)key * M32) >> 32);
        if (b2 <= c2) {
            uint32_t pos = atomicAdd(&m2_s, 1u);
            if (pos < LDS_CAND) lcand[pos] = cv;
            cand2[pos] = cv;
        }
    }
    __syncthreads();
    uint32_t M2 = m2_s;

    if (M2 <= LDS_CAND) {
        for (uint32_t i = t; i < M2; i += 1024) {
            unsigned long long ci = lcand[i];
            uint32_t rank = 0;
            for (uint32_t j = 0; j < M2; ++j) rank += (lcand[j] < ci) ? 1u : 0u;
            if (rank < (uint32_t)K) {
                uint32_t idx = (uint32_t)(ci & 0xFFFFFFFFu);
                out[3 * rank + 0] = pts[3 * idx + 0];
                out[3 * rank + 1] = pts[3 * idx + 1];
                out[3 * rank + 2] = pts[3 * idx + 2];
                out[3 * K + rank] = (float)idx;
            }
        }
    } else {
        for (uint32_t i = t; i < M2; i += 1024) {
            unsigned long long ci = cand2[i];
            uint32_t rank = 0;
            for (uint32_t j = 0; j < M2; ++j) rank += (cand2[j] < ci) ? 1u : 0u;
            if (rank < (uint32_t)K) {
                uint32_t idx = (uint32_t)(ci & 0xFFFFFFFFu);
                out[3 * rank + 0] = pts[3 * idx + 0];
                out[3 * rank + 1] = pts[3 * idx + 1];
                out[3 * rank + 2] = pts[3 * idx + 2];
                out[3 * K + rank] = (float)idx;
            }
        }
    }
}

extern "C" void kernel_launch(void* const* d_in, const int* in_sizes, int n_in,
                              void* d_out, int out_size, void* d_ws, size_t ws_size,
                              hipStream_t stream) {
    const float* pts = (const float*)d_in[0];
    const float* P1  = (const float*)d_in[1];
    float* out = (float*)d_out;

    int N = in_sizes[0] / 3;
    int ntiles = N / TILE_PTS;
    int K = out_size / 4;  // out = K*3 coords + K indices
    int nsamp = N / SRATE;

    uint32_t* w    = (uint32_t*)d_ws;
    uint32_t* cnt  = w + 0;
    uint32_t* cut  = w + 1;
    uint32_t* hist = w + 4;                                            // NBINS
    unsigned long long* cand  = (unsigned long long*)(w + 4 + NBINS);  // CAP u64
    unsigned long long* cand2 = cand + CAP;                            // CAP u64

    int zn = 4 + NBINS;
    zero_kernel<<<(zn + 255) / 256, 256, 0, stream>>>(w, zn);
    sample_hist_kernel<<<256, 256, 0, stream>>>(pts, P1, hist, nsamp);
    scan_kernel<<<1, 256, 0, stream>>>(hist, cut, K);
    filter2_kernel<<<1536, 256, 0, stream>>>(pts, P1, cut, cnt, cand, ntiles, N);
    refine_select_kernel<<<1, 1024, 0, stream>>>(cnt, cut, cand, cand2, pts, out, K);
}